// Round 7
// baseline (121.287 us; speedup 1.0000x reference)
//
#include <hip/hip_runtime.h>
#include <stdint.h>

// Problem dims (fixed by reference)
#define BB   8
#define SS   2048
#define DIN  1024
#define DOUT 64

typedef __bf16 bf16_t;
typedef __bf16 bf16x4 __attribute__((ext_vector_type(4)));
typedef __bf16 bf16x8 __attribute__((ext_vector_type(8)));
typedef float  f32x4  __attribute__((ext_vector_type(4)));
typedef unsigned int u32x4 __attribute__((ext_vector_type(4)));

#define LOG2E 1.44269504088896f

// ---------------------------------------------------------------------------
// Kernel 0: pre-pack weights (1024x64 fp32) into bf16 MFMA B-fragment order.
// Layout: fw[proj][kk=0..31][nt=0..3][lane=0..63][j=0..7]
//   value = W[k][col],  k = kk*32 + (lane>>4)*8 + j,  col = nt*16 + (lane&15)
// Q weights (proj==2) scaled by 1/sqrt(64) = 0.125 (exact).
// ---------------------------------------------------------------------------
__global__ void prep_weights(const float* __restrict__ Kw,
                             const float* __restrict__ Vw,
                             const float* __restrict__ Qw,
                             bf16_t* __restrict__ fw) {
    int proj = blockIdx.x >> 4;
    int seg  = blockIdx.x & 15;
    const float* W = (proj == 0) ? Kw : (proj == 1) ? Vw : Qw;
    float scale = (proj == 2) ? 0.125f : 1.0f;
    bf16_t* out = fw + proj * 65536;
    int base = seg * 4096;
#pragma unroll
    for (int i = 0; i < 16; ++i) {
        int idx  = base + i * 256 + threadIdx.x;
        int j    = idx & 7;
        int lane = (idx >> 3) & 63;
        int nt   = (idx >> 9) & 3;
        int kk   = idx >> 11;
        int k    = kk * 32 + (lane >> 4) * 8 + j;
        int col  = nt * 16 + (lane & 15);
        out[idx] = (bf16_t)(W[k * DOUT + col] * scale);
    }
}

// ---------------------------------------------------------------------------
// Kernel 1: projection GEMM  [16384,1024](fp32) x [1024,64](bf16) -> bf16
//
// Round-7: NON-TEMPORAL A-stream. Six structures (r1-r6) all capped at
// ~2.4 TB/s effective A-read with FETCH_SIZE ~100MB < 192MB demand: ~half
// of X is L3-resident each replay and the L3-HIT service path appears to
// be the ~2.4 TB/s limiter (HBM path measures 6.3 TB/s, m13). nt-loads
// stop X from being (re)allocated into L3 -> steady-state replays stream
// X from HBM. Structure = round-5 (best measured): 16-row tiles, 32KB LDS,
// 4 blocks/CU, batched staging (8 outstanding loads/thread), per-wave
// K-quarter + LDS reduction. Manual B-prefetch dropped (regalloc killed it).
// ---------------------------------------------------------------------------
__global__ __launch_bounds__(256, 4) void proj_kernel(
    const float* __restrict__ Xk, const float* __restrict__ Xv,
    const float* __restrict__ Xq, const bf16_t* __restrict__ fw,
    bf16_t* __restrict__ outK, bf16_t* __restrict__ outV,
    bf16_t* __restrict__ outQ) {
    __shared__ __align__(128) char Alds[32768];   // 16 rows x 2048B bf16, swizzled

    int tid  = threadIdx.x;
    int lane = tid & 63;
    int w    = tid >> 6;    // 0..3 (K-quarter)

    int proj = blockIdx.y;
    const float* X  = (proj == 0) ? Xk : (proj == 1) ? Xv : Xq;
    bf16_t* out     = (proj == 0) ? outK : (proj == 1) ? outV : outQ;
    const bf16_t* fwp = fw + proj * 65536;

    int row0 = blockIdx.x * 16;

    // ---- Phase 1: stage 16 rows (full 4KB rows, contiguous), NT loads ----
#pragma unroll
    for (int b = 0; b < 2; ++b) {
        f32x4 v[8];
#pragma unroll
        for (int j = 0; j < 8; ++j)
            v[j] = __builtin_nontemporal_load(
                       (const f32x4*)(X + (size_t)(row0 + b * 8 + j) * DIN + tid * 4));
#pragma unroll
        for (int j = 0; j < 8; ++j) {
            int row = b * 8 + j;
            bf16x4 bv;
            bv[0] = (bf16_t)v[j][0]; bv[1] = (bf16_t)v[j][1];
            bv[2] = (bf16_t)v[j][2]; bv[3] = (bf16_t)v[j][3];
            *(bf16x4*)(Alds + row * 2048 + ((tid * 8) ^ ((row & 7) << 4))) = bv;
        }
    }
    __syncthreads();

    // ---- Phase 2: MFMA over this wave's K-quarter ----
    f32x4 acc[4];
#pragma unroll
    for (int nt = 0; nt < 4; ++nt) acc[nt] = (f32x4)(0.0f);

    int arow = lane & 15;
    const bf16_t* bq = fwp + (size_t)(w * 8) * 2048 + lane * 8;  // [kk][nt][512]

#pragma unroll
    for (int kkl = 0; kkl < 8; ++kkl) {
        int kb = (w * 256 + kkl * 32 + (lane >> 4) * 8) * 2;   // byte offset in row
        bf16x8 a = *(const bf16x8*)(Alds + arow * 2048 + (kb ^ ((arow & 7) << 4)));
#pragma unroll
        for (int nt = 0; nt < 4; ++nt) {
            bf16x8 b = *(const bf16x8*)(bq + kkl * 2048 + nt * 512);
            acc[nt] = __builtin_amdgcn_mfma_f32_16x16x32_bf16(a, b, acc[nt], 0, 0, 0);
        }
    }

    // ---- Phase 3: reduce K-quarters through LDS (reuse A buffer) ----
    __syncthreads();   // all A-frag reads done
    float* red = (float*)Alds;            // [4][16][64] fp32 = 16 KB
#pragma unroll
    for (int nt = 0; nt < 4; ++nt)
#pragma unroll
        for (int r = 0; r < 4; ++r) {
            int row = (lane >> 4) * 4 + r;
            int col = nt * 16 + (lane & 15);
            red[w * 1024 + row * 64 + col] = acc[nt][r];
        }
    __syncthreads();
    // 256 threads, 4 elements each: col = tid&63, rows (tid>>6)*4 .. +3
#pragma unroll
    for (int i = 0; i < 4; ++i) {
        int row = (tid >> 6) * 4 + i;
        int col = tid & 63;
        float s = red[row * 64 + col] + red[1024 + row * 64 + col] +
                  red[2048 + row * 64 + col] + red[3072 + row * 64 + col];
        out[(size_t)(row0 + row) * DOUT + col] = (bf16_t)s;
    }
}

// ---------------------------------------------------------------------------
// Kernel 2: causal flash attention (round-1 version, unchanged).
// Grid: (32 q-tiles, 8 batches). Block: 256 thr = 4 waves x 16 q-rows.
// ---------------------------------------------------------------------------
__global__ __launch_bounds__(256) void attn_kernel(
    const bf16_t* __restrict__ Kp, const bf16_t* __restrict__ Vp,
    const bf16_t* __restrict__ Qp, float* __restrict__ out) {
    __shared__ __align__(16) bf16_t Klds[64 * 64];      // 8 KB
    __shared__ __align__(16) bf16_t Vlds[64 * 64];      // 8 KB (transposed)
    __shared__ __align__(16) bf16_t Plds[4][16 * 64];   // 8 KB

    int tid   = threadIdx.x;
    int lane  = tid & 63;
    int w     = tid >> 6;
    int qtile = blockIdx.x;
    int batch = blockIdx.y;

    const bf16_t* Kb = Kp + (size_t)batch * SS * DOUT;
    const bf16_t* Vb = Vp + (size_t)batch * SS * DOUT;
    const bf16_t* Qb = Qp + (size_t)batch * SS * DOUT;

    bf16x8 aq[2];
    {
        int r = qtile * 64 + w * 16 + (lane & 15);
        const bf16_t* qp = Qb + (size_t)r * DOUT + (lane >> 4) * 8;
        aq[0] = *(const bf16x8*)(qp);
        aq[1] = *(const bf16x8*)(qp + 32);
    }

    float m[4], lsum[4];
    f32x4 acc[4];
#pragma unroll
    for (int r = 0; r < 4; ++r) { m[r] = -1e30f; lsum[r] = 0.0f; }
#pragma unroll
    for (int nt = 0; nt < 4; ++nt) acc[nt] = (f32x4)(0.0f);

    int ntiles = qtile + 1;
    for (int j = 0; j < ntiles; ++j) {
        __syncthreads();
#pragma unroll
        for (int i = 0; i < 2; ++i) {
            int c   = tid + 256 * i;          // 0..511
            int key = c >> 3;
            int d0  = (c & 7) * 8;
            u32x4 v = *(const u32x4*)(Kb + ((size_t)(j * 64 + key)) * DOUT + d0);
            *(u32x4*)((char*)Klds + key * 128 + ((d0 * 2) ^ ((key & 7) << 4))) = v;
        }
#pragma unroll
        for (int i = 0; i < 2; ++i) {
            int c   = tid + 256 * i;
            int key = c >> 3;
            int d0  = (c & 7) * 8;
            bf16x8 v = *(const bf16x8*)(Vb + ((size_t)(j * 64 + key)) * DOUT + d0);
#pragma unroll
            for (int jj = 0; jj < 8; ++jj) {
                int d = d0 + jj;
                *(bf16_t*)((char*)Vlds + d * 128 + ((key * 2) ^ ((d & 7) << 4))) = v[jj];
            }
        }
        __syncthreads();

        f32x4 sfr[4];
#pragma unroll
        for (int nt = 0; nt < 4; ++nt) sfr[nt] = (f32x4)(0.0f);
#pragma unroll
        for (int kk = 0; kk < 2; ++kk) {
            int d0 = kk * 32 + (lane >> 4) * 8;
#pragma unroll
            for (int nt = 0; nt < 4; ++nt) {
                int key = nt * 16 + (lane & 15);
                bf16x8 bk = *(const bf16x8*)((char*)Klds + key * 128 +
                                             ((d0 * 2) ^ ((key & 7) << 4)));
                sfr[nt] = __builtin_amdgcn_mfma_f32_16x16x32_bf16(aq[kk], bk, sfr[nt], 0, 0, 0);
            }
        }

        if (j == qtile) {
#pragma unroll
            for (int nt = 0; nt < 4; ++nt) {
                int key = nt * 16 + (lane & 15);
#pragma unroll
                for (int r = 0; r < 4; ++r) {
                    int q = w * 16 + (lane >> 4) * 4 + r;
                    if (key > q) sfr[nt][r] = -1e30f;
                }
            }
        }

        float pf[4][4];
#pragma unroll
        for (int r = 0; r < 4; ++r) {
            float mx = fmaxf(fmaxf(sfr[0][r], sfr[1][r]), fmaxf(sfr[2][r], sfr[3][r]));
            mx = fmaxf(mx, __shfl_xor(mx, 1));
            mx = fmaxf(mx, __shfl_xor(mx, 2));
            mx = fmaxf(mx, __shfl_xor(mx, 4));
            mx = fmaxf(mx, __shfl_xor(mx, 8));
            float mn = fmaxf(m[r], mx);
            float scale = exp2f((m[r] - mn) * LOG2E);
            m[r] = mn;
            float rs = 0.0f;
#pragma unroll
            for (int nt = 0; nt < 4; ++nt) {
                float p = exp2f((sfr[nt][r] - mn) * LOG2E);
                pf[nt][r] = p;
                rs += p;
            }
            rs += __shfl_xor(rs, 1);
            rs += __shfl_xor(rs, 2);
            rs += __shfl_xor(rs, 4);
            rs += __shfl_xor(rs, 8);
            lsum[r] = lsum[r] * scale + rs;
#pragma unroll
            for (int nt = 0; nt < 4; ++nt) acc[nt][r] *= scale;
        }

#pragma unroll
        for (int nt = 0; nt < 4; ++nt) {
            int key = nt * 16 + (lane & 15);
#pragma unroll
            for (int r = 0; r < 4; ++r) {
                int q = (lane >> 4) * 4 + r;
                *(bf16_t*)((char*)&Plds[w][0] + q * 128 +
                           ((key * 2) ^ ((q & 7) << 4))) = (bf16_t)pf[nt][r];
            }
        }
        __syncthreads();

#pragma unroll
        for (int kk = 0; kk < 2; ++kk) {
            int k0 = kk * 32 + (lane >> 4) * 8;
            int q  = lane & 15;
            bf16x8 ap = *(const bf16x8*)((char*)&Plds[w][0] + q * 128 +
                                         ((k0 * 2) ^ ((q & 7) << 4)));
#pragma unroll
            for (int nt = 0; nt < 4; ++nt) {
                int d = nt * 16 + (lane & 15);
                bf16x8 bv = *(const bf16x8*)((char*)Vlds + d * 128 +
                                             ((k0 * 2) ^ ((d & 7) << 4)));
                acc[nt] = __builtin_amdgcn_mfma_f32_16x16x32_bf16(ap, bv, acc[nt], 0, 0, 0);
            }
        }
    }

    float* ob = out + ((size_t)batch * SS + qtile * 64 + w * 16) * DOUT;
#pragma unroll
    for (int nt = 0; nt < 4; ++nt) {
#pragma unroll
        for (int r = 0; r < 4; ++r) {
            int q = (lane >> 4) * 4 + r;
            int d = nt * 16 + (lane & 15);
            ob[(size_t)q * DOUT + d] = acc[nt][r] / lsum[r];
        }
    }
}

// ---------------------------------------------------------------------------
// Workspace layout (~6.4 MB):
//   [0, 2MB)   Kp bf16 [8][2048][64]
//   [2, 4MB)   Vp bf16
//   [4, 6MB)   Qp bf16 (pre-scaled by 1/8)
//   [6MB, +384KB) fw bf16 [3][65536] fragment-packed weights
// ---------------------------------------------------------------------------
extern "C" void kernel_launch(void* const* d_in, const int* in_sizes, int n_in,
                              void* d_out, int out_size, void* d_ws, size_t ws_size,
                              hipStream_t stream) {
    const float* Xk = (const float*)d_in[0];
    const float* Xv = (const float*)d_in[1];
    const float* Xq = (const float*)d_in[2];
    const float* Kw = (const float*)d_in[3];
    const float* Vw = (const float*)d_in[4];
    const float* Qw = (const float*)d_in[5];

    bf16_t* Kp = (bf16_t*)d_ws;
    bf16_t* Vp = Kp + (size_t)BB * SS * DOUT;
    bf16_t* Qp = Vp + (size_t)BB * SS * DOUT;
    bf16_t* fw = Qp + (size_t)BB * SS * DOUT;

    prep_weights<<<dim3(48), dim3(256), 0, stream>>>(Kw, Vw, Qw, fw);
    proj_kernel<<<dim3(1024, 3), dim3(256), 0, stream>>>(Xk, Xv, Xq, fw, Kp, Vp, Qp);
    attn_kernel<<<dim3(32, 8), dim3(256), 0, stream>>>(Kp, Vp, Qp, (float*)d_out);
}

// Round 8
// 107.221 us; speedup vs baseline: 1.1312x; 1.1312x over previous
//
#include <hip/hip_runtime.h>
#include <stdint.h>

// Problem dims (fixed by reference)
#define BB   8
#define SS   2048
#define DIN  1024
#define DOUT 64

typedef __bf16 bf16_t;
typedef __bf16 bf16x4 __attribute__((ext_vector_type(4)));
typedef __bf16 bf16x8 __attribute__((ext_vector_type(8)));
typedef float  f32x4  __attribute__((ext_vector_type(4)));
typedef unsigned int u32x4 __attribute__((ext_vector_type(4)));

#define LOG2E 1.44269504088896f

// Async global->LDS, 16B per lane, zero VGPR cost.
__device__ __forceinline__ void load_lds16(const void* g, void* l) {
    __builtin_amdgcn_global_load_lds(
        (const __attribute__((address_space(1))) void*)g,
        (__attribute__((address_space(3))) void*)l, 16, 0, 0);
}

// ---------------------------------------------------------------------------
// Kernel 0: pre-pack weights (1024x64 fp32) into bf16 MFMA B-fragment order.
// Layout: fw[proj][kk=0..31][nt=0..3][lane=0..63][j=0..7]
//   value = W[k][col],  k = kk*32 + (lane>>4)*8 + j,  col = nt*16 + (lane&15)
// Q weights (proj==2) scaled by 1/sqrt(64) = 0.125 (exact).
// ---------------------------------------------------------------------------
__global__ void prep_weights(const float* __restrict__ Kw,
                             const float* __restrict__ Vw,
                             const float* __restrict__ Qw,
                             bf16_t* __restrict__ fw) {
    int proj = blockIdx.x >> 4;
    int seg  = blockIdx.x & 15;
    const float* W = (proj == 0) ? Kw : (proj == 1) ? Vw : Qw;
    float scale = (proj == 2) ? 0.125f : 1.0f;
    bf16_t* out = fw + proj * 65536;
    int base = seg * 4096;
#pragma unroll
    for (int i = 0; i < 16; ++i) {
        int idx  = base + i * 256 + threadIdx.x;
        int j    = idx & 7;
        int lane = (idx >> 3) & 63;
        int nt   = (idx >> 9) & 3;
        int kk   = idx >> 11;
        int k    = kk * 32 + (lane >> 4) * 8 + j;
        int col  = nt * 16 + (lane & 15);
        out[idx] = (bf16_t)(W[k * DOUT + col] * scale);
    }
}

// ---------------------------------------------------------------------------
// Kernel 1: projection GEMM (round-6 structure: async global_load_lds).
// For proj==1 (V) the output is written TRANSPOSED (VpT[b][d][s]) via a
// swizzled-LDS bounce so attention's PV B-fragments can be loaded straight
// from global memory with 16B contiguous reads.
// ---------------------------------------------------------------------------
__global__ __launch_bounds__(256) void proj_kernel(
    const float* __restrict__ Xk, const float* __restrict__ Xv,
    const float* __restrict__ Xq, const bf16_t* __restrict__ fw,
    bf16_t* __restrict__ outK, bf16_t* __restrict__ outVT,
    bf16_t* __restrict__ outQ) {
    __shared__ __align__(128) char Al[8192];   // A tile [32 rows][256B], swizzled
    __shared__ __align__(128) char Bl[8192];   // B slice

    int tid  = threadIdx.x;
    int lane = tid & 63;
    int w    = tid >> 6;    // 0..3

    int proj = blockIdx.y;
    const float* X  = (proj == 0) ? Xk : (proj == 1) ? Xv : Xq;
    bf16_t* out     = (proj == 0) ? outK : (proj == 1) ? outVT : outQ;
    const bf16_t* fwp = fw + proj * 65536;

    int row0 = blockIdx.x * 32;

    // staging source: thread t covers (row0 + i*16 + (t>>4), 16B-block (t&15)^(t>>4))
    const float* ga = X + (size_t)(row0 + (tid >> 4)) * DIN + ((tid & 15) ^ (tid >> 4)) * 4;
    char* alds0 = Al + (w << 10);
    char* alds1 = Al + 4096 + (w << 10);
    char* blds0 = Bl + (w << 10);
    char* blds1 = Bl + 4096 + (w << 10);

    f32x4 acc0 = (f32x4)(0.0f), acc1 = (f32x4)(0.0f);
    int r   = (w & 1) * 16 + (lane & 15);     // tile-local row for A-frags
    int nt0 = (w >> 1) * 2;

    for (int kt = 0; kt < 16; ++kt) {
        load_lds16(ga + kt * 64,               alds0);
        load_lds16(ga + 16 * DIN + kt * 64,    alds1);
        load_lds16(fwp + kt * 4096 + tid * 8,        blds0);
        load_lds16(fwp + kt * 4096 + 2048 + tid * 8, blds1);
        __syncthreads();

#pragma unroll
        for (int s = 0; s < 2; ++s) {
            int b0 = s * 8 + (lane >> 4) * 2;        // logical 16B blocks
            f32x4 lo = *(const f32x4*)(Al + r * 256 + (((b0    ) ^ (lane & 15)) << 4));
            f32x4 hi = *(const f32x4*)(Al + r * 256 + (((b0 + 1) ^ (lane & 15)) << 4));
            bf16x8 af;
            af[0] = (bf16_t)lo[0]; af[1] = (bf16_t)lo[1];
            af[2] = (bf16_t)lo[2]; af[3] = (bf16_t)lo[3];
            af[4] = (bf16_t)hi[0]; af[5] = (bf16_t)hi[1];
            af[6] = (bf16_t)hi[2]; af[7] = (bf16_t)hi[3];
            bf16x8 bf0 = *(const bf16x8*)(Bl + s * 4096 + nt0 * 1024 + lane * 16);
            bf16x8 bf1 = *(const bf16x8*)(Bl + s * 4096 + (nt0 + 1) * 1024 + lane * 16);
            acc0 = __builtin_amdgcn_mfma_f32_16x16x32_bf16(af, bf0, acc0, 0, 0, 0);
            acc1 = __builtin_amdgcn_mfma_f32_16x16x32_bf16(af, bf1, acc1, 0, 0, 0);
        }
        __syncthreads();
    }

    if (proj != 1) {
        // direct store: C/D layout col = lane&15, row = (lane>>4)*4 + j
#pragma unroll
        for (int j = 0; j < 4; ++j) {
            int orow = row0 + (w & 1) * 16 + (lane >> 4) * 4 + j;
            out[(size_t)orow * DOUT + nt0 * 16 + (lane & 15)]       = (bf16_t)acc0[j];
            out[(size_t)orow * DOUT + (nt0 + 1) * 16 + (lane & 15)] = (bf16_t)acc1[j];
        }
    } else {
        // bounce C-tile through swizzled LDS, emit V^T [b][d][s] coalesced
#pragma unroll
        for (int j = 0; j < 4; ++j) {
            int row = (w & 1) * 16 + (lane >> 4) * 4 + j;
            int c0  = nt0 * 16 + (lane & 15);
            int c1  = c0 + 16;
            *(bf16_t*)(Al + row * 128 + ((c0 * 2) ^ ((row & 7) << 4))) = (bf16_t)acc0[j];
            *(bf16_t*)(Al + row * 128 + ((c1 * 2) ^ ((row & 7) << 4))) = (bf16_t)acc1[j];
        }
        __syncthreads();
        int b  = row0 >> 11;          // batch
        int s0 = row0 & 2047;         // seq offset within batch
        int sl = tid & 31;
        int d0 = (tid >> 5) * 8;
        bf16_t vals[8];
#pragma unroll
        for (int j = 0; j < 8; ++j)
            vals[j] = *(const bf16_t*)(Al + sl * 128 + (((d0 + j) * 2) ^ ((sl & 7) << 4)));
#pragma unroll
        for (int j = 0; j < 8; ++j)
            out[(size_t)b * (DOUT * SS) + (size_t)(d0 + j) * SS + s0 + sl] = vals[j];
    }
}

// ---------------------------------------------------------------------------
// Kernel 2: causal flash attention, BARRIER-FREE inner loop.
// K/V read directly from L2-resident global (K natural layout for QK^T
// B-frags; V^T layout for PV B-frags) — no K/V LDS staging at all.
// Split-KV: qt<16 -> 1 block; qt>=16 -> 2 blocks (halves of the key range),
// partial (O, m, l) to workspace, merged by attn_combine. Max 16 tile-steps
// per block (vs 32 before). Grid (48, 8) split / (32, 8) fallback.
// ---------------------------------------------------------------------------
__global__ __launch_bounds__(256) void attn_kernel(
    const bf16_t* __restrict__ Kp, const bf16_t* __restrict__ VpT,
    const bf16_t* __restrict__ Qp, float* __restrict__ out,
    float* __restrict__ Opart, float* __restrict__ Oml, int split) {
    __shared__ __align__(16) char Plds[4][2048];   // per-wave P buffer

    int tid  = threadIdx.x;
    int lane = tid & 63;
    int w    = tid >> 6;
    int idx  = blockIdx.x;
    int b    = blockIdx.y;

    int qt, t0, t1, half = 0;
    bool partial;
    if (!split || idx < 16) { qt = idx; t0 = 0; t1 = qt + 1; partial = false; }
    else {
        int e = idx - 16;
        qt   = 16 + (e >> 1);
        half = e & 1;
        int T = qt + 1, h = (T + 1) >> 1;
        t0 = half ? h : 0;
        t1 = half ? T : h;
        partial = true;
    }

    const bf16_t* Kb = Kp  + (size_t)b * SS * DOUT;
    const bf16_t* Vb = VpT + (size_t)b * DOUT * SS;
    const bf16_t* Qb = Qp  + (size_t)b * SS * DOUT;

    // Q fragments (already scaled by 1/8)
    bf16x8 aq0, aq1;
    {
        int rq = qt * 64 + w * 16 + (lane & 15);
        const bf16_t* qp = Qb + (size_t)rq * DOUT + (lane >> 4) * 8;
        aq0 = *(const bf16x8*)(qp);
        aq1 = *(const bf16x8*)(qp + 32);
    }

    float m[4], lsum[4];
    f32x4 acc[4];
#pragma unroll
    for (int r = 0; r < 4; ++r) { m[r] = -1e30f; lsum[r] = 0.0f; }
#pragma unroll
    for (int nt = 0; nt < 4; ++nt) acc[nt] = (f32x4)(0.0f);

    char* Pw = &Plds[w][0];

    for (int t = t0; t < t1; ++t) {
        // ---- S = Q K^T : B-frags direct from global K (natural layout) ----
        f32x4 sfr[4];
#pragma unroll
        for (int nt = 0; nt < 4; ++nt) sfr[nt] = (f32x4)(0.0f);
#pragma unroll
        for (int kk = 0; kk < 2; ++kk) {
            int d0 = kk * 32 + (lane >> 4) * 8;
#pragma unroll
            for (int nt = 0; nt < 4; ++nt) {
                int key = nt * 16 + (lane & 15);
                bf16x8 bk = *(const bf16x8*)(Kb + (size_t)(t * 64 + key) * DOUT + d0);
                sfr[nt] = __builtin_amdgcn_mfma_f32_16x16x32_bf16(
                              kk == 0 ? aq0 : aq1, bk, sfr[nt], 0, 0, 0);
            }
        }

        // ---- causal mask (diagonal tile only) ----
        if (t == qt) {
#pragma unroll
            for (int nt = 0; nt < 4; ++nt) {
                int key = nt * 16 + (lane & 15);
#pragma unroll
                for (int r = 0; r < 4; ++r) {
                    int q = w * 16 + (lane >> 4) * 4 + r;
                    if (key > q) sfr[nt][r] = -1e30f;
                }
            }
        }

        // ---- online softmax (rows live in 16-lane groups) ----
        float pf[4][4];
#pragma unroll
        for (int r = 0; r < 4; ++r) {
            float mx = fmaxf(fmaxf(sfr[0][r], sfr[1][r]), fmaxf(sfr[2][r], sfr[3][r]));
            mx = fmaxf(mx, __shfl_xor(mx, 1));
            mx = fmaxf(mx, __shfl_xor(mx, 2));
            mx = fmaxf(mx, __shfl_xor(mx, 4));
            mx = fmaxf(mx, __shfl_xor(mx, 8));
            float mn = fmaxf(m[r], mx);
            float scale = exp2f((m[r] - mn) * LOG2E);
            m[r] = mn;
            float rs = 0.0f;
#pragma unroll
            for (int nt = 0; nt < 4; ++nt) {
                float p = exp2f((sfr[nt][r] - mn) * LOG2E);
                pf[nt][r] = p;
                rs += p;
            }
            rs += __shfl_xor(rs, 1);
            rs += __shfl_xor(rs, 2);
            rs += __shfl_xor(rs, 4);
            rs += __shfl_xor(rs, 8);
            lsum[r] = lsum[r] * scale + rs;
#pragma unroll
            for (int nt = 0; nt < 4; ++nt) acc[nt][r] *= scale;
        }

        // ---- P -> per-wave LDS (bf16, swizzled); wave-internal, no barrier ----
#pragma unroll
        for (int nt = 0; nt < 4; ++nt) {
            int key = nt * 16 + (lane & 15);
#pragma unroll
            for (int r = 0; r < 4; ++r) {
                int q = (lane >> 4) * 4 + r;
                *(bf16_t*)(Pw + q * 128 + ((key * 2) ^ ((q & 7) << 4))) = (bf16_t)pf[nt][r];
            }
        }

        // ---- O += P V : B-frags direct from global V^T ----
#pragma unroll
        for (int kk = 0; kk < 2; ++kk) {
            int k0 = kk * 32 + (lane >> 4) * 8;
            int q  = lane & 15;
            bf16x8 ap = *(const bf16x8*)(Pw + q * 128 + ((k0 * 2) ^ ((q & 7) << 4)));
#pragma unroll
            for (int nt = 0; nt < 4; ++nt) {
                int d = nt * 16 + (lane & 15);
                bf16x8 bv = *(const bf16x8*)(Vb + (size_t)d * SS + t * 64 + k0);
                acc[nt] = __builtin_amdgcn_mfma_f32_16x16x32_bf16(ap, bv, acc[nt], 0, 0, 0);
            }
        }
    }

    if (!partial) {
        float* ob = out + ((size_t)b * SS + qt * 64 + w * 16) * DOUT;
#pragma unroll
        for (int nt = 0; nt < 4; ++nt)
#pragma unroll
            for (int r = 0; r < 4; ++r) {
                int q = (lane >> 4) * 4 + r;
                int d = nt * 16 + (lane & 15);
                ob[(size_t)q * DOUT + d] = acc[nt][r] / lsum[r];
            }
    } else {
        size_t pbase = (((size_t)b * 16 + (qt - 16)) * 2 + half);
        float* Op = Opart + pbase * 4096;
        float* Ml = Oml   + pbase * 128;
#pragma unroll
        for (int nt = 0; nt < 4; ++nt)
#pragma unroll
            for (int r = 0; r < 4; ++r) {
                int row = w * 16 + (lane >> 4) * 4 + r;
                Op[row * 64 + nt * 16 + (lane & 15)] = acc[nt][r];
            }
        if ((lane & 15) == 0) {
#pragma unroll
            for (int r = 0; r < 4; ++r) {
                int row = w * 16 + (lane >> 4) * 4 + r;
                Ml[row * 2]     = m[r];
                Ml[row * 2 + 1] = lsum[r];
            }
        }
    }
}

// ---------------------------------------------------------------------------
// Kernel 3: merge the two split-KV partials for qt>=16. Grid (16, 8), 256 thr.
// ---------------------------------------------------------------------------
__global__ __launch_bounds__(256) void attn_combine(
    const float* __restrict__ Opart, const float* __restrict__ Oml,
    float* __restrict__ out) {
    int qt  = 16 + blockIdx.x;
    int b   = blockIdx.y;
    int tid = threadIdx.x;
    int row = tid >> 2;
    int cb  = (tid & 3) * 16;

    size_t base = ((size_t)b * 16 + (qt - 16)) * 2;
    const float* O0 = Opart + base * 4096;
    const float* O1 = O0 + 4096;
    const float* M0 = Oml + base * 128;
    const float* M1 = M0 + 128;

    float m0 = M0[row * 2], l0 = M0[row * 2 + 1];
    float m1 = M1[row * 2], l1 = M1[row * 2 + 1];
    float mm = fmaxf(m0, m1);
    float e0 = exp2f((m0 - mm) * LOG2E);
    float e1 = exp2f((m1 - mm) * LOG2E);
    float li = 1.0f / (l0 * e0 + l1 * e1);

    const float* p0 = O0 + row * 64 + cb;
    const float* p1 = O1 + row * 64 + cb;
    float* ob = out + ((size_t)b * SS + qt * 64 + row) * DOUT + cb;
#pragma unroll
    for (int i = 0; i < 4; ++i) {
        f32x4 a = *(const f32x4*)(p0 + i * 4);
        f32x4 c = *(const f32x4*)(p1 + i * 4);
        f32x4 o;
#pragma unroll
        for (int j = 0; j < 4; ++j) o[j] = (a[j] * e0 + c[j] * e1) * li;
        *(f32x4*)(ob + i * 4) = o;
    }
}

// ---------------------------------------------------------------------------
// Workspace layout (~10.5 MB):
//   [0, 2MB)       Kp  bf16 [8][2048][64]
//   [2MB, 4MB)     VpT bf16 [8][64][2048]   (TRANSPOSED)
//   [4MB, 6MB)     Qp  bf16 (pre-scaled by 1/8)
//   [6MB, +384KB)  fw  bf16 [3][65536]
//   [+4MB]         Opart f32 [8][16][2][64][64]
//   [+128KB]       Oml   f32 [8][16][2][64][2]
// Fallback if ws_size too small: no-split attention (grid 32x8), no combine.
// ---------------------------------------------------------------------------
extern "C" void kernel_launch(void* const* d_in, const int* in_sizes, int n_in,
                              void* d_out, int out_size, void* d_ws, size_t ws_size,
                              hipStream_t stream) {
    const float* Xk = (const float*)d_in[0];
    const float* Xv = (const float*)d_in[1];
    const float* Xq = (const float*)d_in[2];
    const float* Kw = (const float*)d_in[3];
    const float* Vw = (const float*)d_in[4];
    const float* Qw = (const float*)d_in[5];

    bf16_t* Kp  = (bf16_t*)d_ws;
    bf16_t* VpT = Kp  + (size_t)BB * SS * DOUT;
    bf16_t* Qp  = VpT + (size_t)BB * SS * DOUT;
    bf16_t* fw  = Qp  + (size_t)BB * SS * DOUT;
    char*   pend = (char*)(fw + 3 * 65536);
    float*  Opart = (float*)pend;
    float*  Oml   = Opart + (size_t)8 * 16 * 2 * 4096;

    size_t need = (size_t)((char*)(Oml + 8 * 16 * 2 * 128) - (char*)d_ws);
    int split = (ws_size >= need) ? 1 : 0;

    prep_weights<<<dim3(48), dim3(256), 0, stream>>>(Kw, Vw, Qw, fw);
    proj_kernel<<<dim3(512, 3), dim3(256), 0, stream>>>(Xk, Xv, Xq, fw, Kp, VpT, Qp);
    attn_kernel<<<dim3(split ? 48 : 32, 8), dim3(256), 0, stream>>>(
        Kp, VpT, Qp, (float*)d_out, Opart, Oml, split);
    if (split)
        attn_combine<<<dim3(16, 8), dim3(256), 0, stream>>>(Opart, Oml, (float*)d_out);
}